// Round 17
// baseline (68.927 us; speedup 1.0000x reference)
//
#include <hip/hip_runtime.h>
#include <math.h>

#define B_      32
#define NP1     2001
#define D_      512
#define R_      6
#define NROLES  190
#define NVERBS  504
#define VOCAB   2001
#define NREG    2000

#define NSPL    64          // splits per b -> 2048 main blocks
#define K1CH    32          // rows per block
#define PSTRIDE 3592        // 6*512 (SW) + 512 (rsum) + 8 (sumexp+pad)
#define NUQ     16          // u-partial splits
// workspace layout (floats)
#define WS_U    8                        // 16*190 = 3040 floats
#define WS_PART 3048
#define WS_AB   (3048 + 7356416)         // part = 32*64*3592; AB = 192*512 ushort
#define WS_WLB  (WS_AB + 49152)          // ushort Wlb[2048*512]

typedef __attribute__((ext_vector_type(8))) short  short8v;
typedef __attribute__((ext_vector_type(8))) unsigned short ushort8v;
typedef __attribute__((ext_vector_type(4))) float  f32x4;
typedef __attribute__((ext_vector_type(2))) unsigned int uint2v;

__device__ __forceinline__ float fast_tanh(float x) {
    float e = exp2f(x * 2.885390082f);
    return 1.0f - 2.0f * __builtin_amdgcn_rcpf(e + 1.0f);
}
__device__ __forceinline__ float fast_exp(float x) {
    return exp2f(x * 1.442695041f);
}
__device__ __forceinline__ unsigned short f2bf(float f) {   // RNE
    unsigned u = __float_as_uint(f);
    return (unsigned short)((u + 0x7FFFu + ((u >> 16) & 1u)) >> 16);
}

// 64-lane sum, all lanes get result. PURE VALU: 4 DPP + permlane16/32_swap.
__device__ __forceinline__ float wave_sum(float v) {
    int x;
    x = __builtin_amdgcn_update_dpp(0, __float_as_int(v), 0xB1, 0xF, 0xF, true);
    v += __int_as_float(x);
    x = __builtin_amdgcn_update_dpp(0, __float_as_int(v), 0x4E, 0xF, 0xF, true);
    v += __int_as_float(x);
    x = __builtin_amdgcn_update_dpp(0, __float_as_int(v), 0x124, 0xF, 0xF, true);
    v += __int_as_float(x);
    x = __builtin_amdgcn_update_dpp(0, __float_as_int(v), 0x128, 0xF, 0xF, true);
    v += __int_as_float(x);
    uint2v p = __builtin_amdgcn_permlane16_swap(__float_as_uint(v), __float_as_uint(v), false, false);
    v = __uint_as_float(p[0]) + __uint_as_float(p[1]);
    p = __builtin_amdgcn_permlane32_swap(__float_as_uint(v), __float_as_uint(v), false, false);
    v = __uint_as_float(p[0]) + __uint_as_float(p[1]);
    return v;
}

// async global->LDS, 16B/lane; LDS dest = l + lane*16 (HW adds lane offset)
__device__ __forceinline__ void gload_lds16(const float* g, float* l) {
    __builtin_amdgcn_global_load_lds(
        (const __attribute__((address_space(1))) void*)g,
        (__attribute__((address_space(3))) void*)l, 16, 0, 0);
}

// ---------------- K0: u[q][k] = sum_{d in q*32..} Wr[d][k]*Wa[d] ----------------
__global__ __launch_bounds__(256) void k0_upart(
    const float* __restrict__ Wr, const float* __restrict__ Wa,
    float* __restrict__ ws_u) {
    const int q = blockIdx.x;           // 16 blocks, 32 d each
    const int k = threadIdx.x;
    if (k >= NROLES) return;
    float s = 0.f;
    const int d0 = q * 32;
    #pragma unroll 8
    for (int d = 0; d < 32; ++d)
        s += Wr[(size_t)(d0 + d) * NROLES + k] * Wa[d0 + d];
    ws_u[q * NROLES + k] = s;
}

// ---------------- K1: {main pass (2048 blk, 32 rows)} ∪ {Wl cast (512)} ∪ {verb (64)} ----------------
// Single-row ring slots: 16.5 KB LDS/block -> HW can pack 8 blocks/CU (VGPR ~60 <= 64).
__global__ __launch_bounds__(256, 4) void k1_fused(
    const float* __restrict__ vs, const float* __restrict__ Wa,
    const float* __restrict__ roles, const float* __restrict__ br,
    const float* __restrict__ ba, const float* __restrict__ ws_u,
    float* __restrict__ part,
    const float* __restrict__ Wl, unsigned short* __restrict__ Wlb,
    const float* __restrict__ Wv, const float* __restrict__ bv,
    float* __restrict__ out_verb) {
    const int bid = blockIdx.x;
    const int tid = threadIdx.x;

    __shared__ __align__(16) float smem[4 * 2 * 512];    // 16 KB rings; reused for merge / verb a_s
    __shared__ float lse_[4][R_];

    if (bid >= B_ * NSPL) {
        if (bid < B_ * NSPL + 512) {
            // ---- Wl cast: 2048 rows (pad >=2001 with 0), 512 cols ----
            const int ci = bid - B_ * NSPL;
            const int idx = ci * 2048 + tid * 8;
            const int row = idx >> 9;
            const int col = idx & 511;
            ushort8v o;
            if (row < VOCAB) {
                float4 a = *reinterpret_cast<const float4*>(Wl + (size_t)row * D_ + col);
                float4 b = *reinterpret_cast<const float4*>(Wl + (size_t)row * D_ + col + 4);
                o[0] = f2bf(a.x); o[1] = f2bf(a.y); o[2] = f2bf(a.z); o[3] = f2bf(a.w);
                o[4] = f2bf(b.x); o[5] = f2bf(b.y); o[6] = f2bf(b.z); o[7] = f2bf(b.w);
            } else {
                o = (ushort8v)0;
            }
            *reinterpret_cast<ushort8v*>(Wlb + idx) = o;
        } else {
            // ---- verb head ----
            const int q = bid - (B_ * NSPL + 512);   // 0..63
            const int b = q >> 1;
            const int g = q & 1;
            float* a_s = smem;
            float2 x = reinterpret_cast<const float2*>(vs + (size_t)b * (NP1 * D_))[tid];
            reinterpret_cast<float2*>(a_s)[tid] = make_float2(fmaxf(x.x, 0.f), fmaxf(x.y, 0.f));
            __syncthreads();
            const int v = g * 252 + tid;
            if (tid < 252 && v < NVERBS) {
                const float* wrow = Wv + (size_t)v * D_;
                float s = 0.f;
                #pragma unroll 4
                for (int k = 0; k < D_; k += 4) {
                    float4 w4 = *reinterpret_cast<const float4*>(wrow + k);
                    s += a_s[k] * w4.x + a_s[k + 1] * w4.y + a_s[k + 2] * w4.z + a_s[k + 3] * w4.w;
                }
                out_verb[b * NVERBS + v] = s + bv[v];
            }
        }
        return;
    }

    const int b     = bid / NSPL;
    const int split = bid % NSPL;
    const int lane  = tid & 63;
    const int w     = tid >> 6;
    float* ring = smem + w * 1024;                       // 2 slots x 512 floats

    const float4 wvA = *reinterpret_cast<const float4*>(Wa + D_ + lane * 4);
    const float4 wvB = *reinterpret_cast<const float4*>(Wa + D_ + 256 + lane * 4);

    const float* base = vs + (size_t)b * (NP1 * D_) + D_;
    const int n0 = split * K1CH;
    const int nrows = min(n0 + K1CH, NREG) - n0;         // 32, 16, or <=0
    const int cnt = (nrows > 0) ? ((nrows - w + 3) >> 2) : 0;   // rows this wave

    // ---- stage first two rows (wave w owns rows n0+w+4i) ----
    #pragma unroll
    for (int k = 0; k < 2; ++k) {
        if (k < cnt) {
            const float* g0 = base + (size_t)(n0 + w + 4 * k) * D_ + lane * 4;
            float* s0 = ring + k * 512;
            gload_lds16(g0, s0);
            gload_lds16(g0 + 256, s0 + 256);
        }
    }
    asm volatile("" ::: "memory");

    // ---- inline s_role (L2-resident reads; overlaps ring latency) ----
    float sr[R_];
    {
        float pr[R_] = {0.f, 0.f, 0.f, 0.f, 0.f, 0.f};
        #pragma unroll
        for (int i = 0; i < 3; ++i) {
            const int k = lane + i * 64;
            if (k < NROLES) {
                float u = 0.f;
                #pragma unroll
                for (int q = 0; q < NUQ; ++q) u += ws_u[q * NROLES + k];
                #pragma unroll
                for (int r = 0; r < R_; ++r) pr[r] += roles[r * NROLES + k] * u;
            }
        }
        float c0 = 0.f;
        #pragma unroll
        for (int i = 0; i < 8; ++i) c0 += Wa[lane + i * 64] * br[lane + i * 64];
        c0 = wave_sum(c0) + ba[0];
        #pragma unroll
        for (int r = 0; r < R_; ++r) sr[r] = wave_sum(pr[r]) + c0;
    }

    float acc[R_][8];
    float rsum[8];
    float sume[R_];
    #pragma unroll
    for (int r = 0; r < R_; ++r) {
        sume[r] = 0.f;
        #pragma unroll
        for (int j = 0; j < 8; ++j) acc[r][j] = 0.f;
    }
    #pragma unroll
    for (int j = 0; j < 8; ++j) rsum[j] = 0.f;

    asm volatile("" ::: "memory");

    int st = 2;
    for (int i = 0; i < cnt; ++i) {
        const int rem = cnt - i;          // outstanding rows = min(2, rem)
        if (rem > 1) asm volatile("s_waitcnt vmcnt(2)" ::: "memory");
        else         asm volatile("s_waitcnt vmcnt(0)" ::: "memory");

        const float* l0 = ring + (i & 1) * 512;
        float4 xA = *reinterpret_cast<const float4*>(l0 + lane * 4);
        float4 xB = *reinterpret_cast<const float4*>(l0 + 256 + lane * 4);
        // consume (forces lgkm wait) BEFORE overwriting the slot
        float d = xA.x*wvA.x + xA.y*wvA.y + xA.z*wvA.z + xA.w*wvA.w
                + xB.x*wvB.x + xB.y*wvB.y + xB.z*wvB.z + xB.w*wvB.w;
        if (st < cnt) {                    // refill the slot just consumed
            const float* g0 = base + (size_t)(n0 + w + 4 * st) * D_ + lane * 4;
            float* s0 = ring + (st & 1) * 512;
            gload_lds16(g0, s0);
            gload_lds16(g0 + 256, s0 + 256);
            ++st;
        }
        d = wave_sum(d);
        float xs[8] = {xA.x, xA.y, xA.z, xA.w, xB.x, xB.y, xB.z, xB.w};
        #pragma unroll
        for (int r = 0; r < R_; ++r) {
            float t = fast_tanh(sr[r] + d);
            sume[r] += fast_exp(t);
            #pragma unroll
            for (int j = 0; j < 8; ++j) acc[r][j] += t * xs[j];
        }
        #pragma unroll
        for (int j = 0; j < 8; ++j) rsum[j] += xs[j];
    }

    // merge the 4 waves into smem[0..3583] (reused -> barrier first)
    __syncthreads();
    float* ls = smem;
    for (int ww = 0; ww < 4; ++ww) {
        if (w == ww) {
            #pragma unroll
            for (int j = 0; j < 8; ++j) {
                const int dd = (j < 4) ? (lane * 4 + j) : (256 + lane * 4 + (j - 4));
                if (ww == 0) {
                    #pragma unroll
                    for (int r = 0; r < R_; ++r) ls[r * D_ + dd] = acc[r][j];
                    ls[6 * D_ + dd] = rsum[j];
                } else {
                    #pragma unroll
                    for (int r = 0; r < R_; ++r) ls[r * D_ + dd] += acc[r][j];
                    ls[6 * D_ + dd] += rsum[j];
                }
            }
            if (lane == 0) {
                #pragma unroll
                for (int r = 0; r < R_; ++r) lse_[ww][r] = sume[r];
            }
        }
        __syncthreads();
    }
    float* dst = part + (size_t)(b * NSPL + split) * PSTRIDE;
    for (int i = tid; i < 3584 / 4; i += 256)
        reinterpret_cast<float4*>(dst)[i] = reinterpret_cast<const float4*>(ls)[i];
    if (tid < R_)
        dst[3584 + tid] = lse_[0][tid] + lse_[1][tid] + lse_[2][tid] + lse_[3][tid];
}

// ---------------- K2: reduce 64 partials -> relu(label_embed) as bf16 ----------------
__global__ __launch_bounds__(256) void k2_reduce(
    const float* __restrict__ part, unsigned short* __restrict__ AB) {
    const int bid = blockIdx.x;
    const int t = threadIdx.x;
    const int b = bid >> 3;
    const int chunk = bid & 7;
    const int dl = t & 63;
    const int qg = t >> 6;
    const int d = chunk * 64 + dl;
    const float* pb = part + (size_t)b * NSPL * PSTRIDE;

    float s[7] = {0.f, 0.f, 0.f, 0.f, 0.f, 0.f, 0.f};
    for (int q = qg * 16; q < qg * 16 + 16; ++q) {
        const float* p = pb + (size_t)q * PSTRIDE;
        #pragma unroll
        for (int r = 0; r < R_; ++r) s[r] += p[r * D_ + d];
        s[6] += p[6 * D_ + d];
    }
    __shared__ float red[4][7][64];
    #pragma unroll
    for (int i = 0; i < 7; ++i) red[qg][i][dl] = s[i];
    __shared__ float lse_s[R_];
    if (t < R_) {
        float se = 0.f;
        for (int q = 0; q < NSPL; ++q) se += pb[(size_t)q * PSTRIDE + 3584 + t];
        lse_s[t] = logf(se);
    }
    __syncthreads();
    if (t < 64) {
        float rs = red[0][6][dl] + red[1][6][dl] + red[2][6][dl] + red[3][6][dl];
        #pragma unroll
        for (int r = 0; r < R_; ++r) {
            float sw = red[0][r][dl] + red[1][r][dl] + red[2][r][dl] + red[3][r][dl];
            AB[(size_t)(b * R_ + r) * D_ + d] = f2bf(fmaxf(sw - lse_s[r] * rs, 0.f));
        }
    }
}

// ---------------- K3: bf16 MFMA gemm, out = relu(A) @ Wl^T + bl ----------------
// one wave-tile (16m x 64v) per 64-thread block; 384 blocks -> all CUs busy.
__global__ __launch_bounds__(64) void k3_mfma(
    const unsigned short* __restrict__ AB, const unsigned short* __restrict__ Wlb,
    const float* __restrict__ bl, float* __restrict__ out_role) {
    const int lane = threadIdx.x;
    const int wt   = blockIdx.x;             // 0..383
    const int mt   = wt >> 5;                // 0..11
    const int vt   = wt & 31;                // 0..31
    const int m0   = mt * 16;
    const int v0   = vt * 64;
    const int rc   = lane & 15;              // A-row (m) and B-col (v) sub-index
    const int kg   = lane >> 4;              // k-group

    const unsigned short* arow = AB + (size_t)(m0 + rc) * D_ + kg * 8;
    f32x4 acc0 = {0.f, 0.f, 0.f, 0.f}, acc1 = {0.f, 0.f, 0.f, 0.f};
    f32x4 acc2 = {0.f, 0.f, 0.f, 0.f}, acc3 = {0.f, 0.f, 0.f, 0.f};

    #pragma unroll 4
    for (int ks = 0; ks < 16; ++ks) {
        const int kb = ks * 32;
        short8v af = *reinterpret_cast<const short8v*>(arow + kb);
        const unsigned short* wb = Wlb + (size_t)(v0 + rc) * D_ + kg * 8 + kb;
        short8v b0 = *reinterpret_cast<const short8v*>(wb);
        short8v b1 = *reinterpret_cast<const short8v*>(wb + 16 * D_);
        short8v b2 = *reinterpret_cast<const short8v*>(wb + 32 * D_);
        short8v b3 = *reinterpret_cast<const short8v*>(wb + 48 * D_);
        acc0 = __builtin_amdgcn_mfma_f32_16x16x32_bf16(af, b0, acc0, 0, 0, 0);
        acc1 = __builtin_amdgcn_mfma_f32_16x16x32_bf16(af, b1, acc1, 0, 0, 0);
        acc2 = __builtin_amdgcn_mfma_f32_16x16x32_bf16(af, b2, acc2, 0, 0, 0);
        acc3 = __builtin_amdgcn_mfma_f32_16x16x32_bf16(af, b3, acc3, 0, 0, 0);
    }
    f32x4 accs[4] = {acc0, acc1, acc2, acc3};
    #pragma unroll
    for (int f = 0; f < 4; ++f) {
        const int v = v0 + f * 16 + rc;
        if (v < VOCAB) {
            const float bb = bl[v];
            #pragma unroll
            for (int j = 0; j < 4; ++j) {
                const int m = m0 + kg * 4 + j;
                out_role[(size_t)m * VOCAB + v] = accs[f][j] + bb;
            }
        }
    }
}

extern "C" void kernel_launch(void* const* d_in, const int* in_sizes, int n_in,
                              void* d_out, int out_size, void* d_ws, size_t ws_size,
                              hipStream_t stream) {
    const float* vs    = (const float*)d_in[0];
    const float* roles = (const float*)d_in[1];
    const float* Wr    = (const float*)d_in[2];
    const float* br    = (const float*)d_in[3];
    const float* Wa    = (const float*)d_in[4];
    const float* ba    = (const float*)d_in[5];
    const float* Wv    = (const float*)d_in[6];
    const float* bv    = (const float*)d_in[7];
    const float* Wl    = (const float*)d_in[8];
    const float* bl    = (const float*)d_in[9];

    float* out_verb = (float*)d_out;
    float* out_role = (float*)d_out + B_ * NVERBS;
    float* ws       = (float*)d_ws;
    unsigned short* AB  = (unsigned short*)(ws + WS_AB);
    unsigned short* Wlb = (unsigned short*)(ws + WS_WLB);

    k0_upart<<<dim3(NUQ), dim3(256), 0, stream>>>(Wr, Wa, ws + WS_U);
    k1_fused<<<dim3(B_ * NSPL + 512 + 64), dim3(256), 0, stream>>>(
        vs, Wa, roles, br, ba, ws + WS_U, ws + WS_PART,
        Wl, Wlb, Wv, bv, out_verb);
    k2_reduce<<<dim3(256), dim3(256), 0, stream>>>(ws + WS_PART, AB);
    k3_mfma<<<dim3(384), dim3(64), 0, stream>>>(AB, Wlb, bl, out_role);
}

// Round 18
// 59.634 us; speedup vs baseline: 1.1558x; 1.1558x over previous
//
#include <hip/hip_runtime.h>
#include <math.h>

#define B_      32
#define NP1     2001
#define D_      512
#define R_      6
#define NROLES  190
#define NVERBS  504
#define VOCAB   2001
#define NREG    2000

#define NSPLIT  32
#define CHUNK   64
#define PH_STRIDE 3584      // bf16 partial stride (6*512 SW + 512 rsum) in ushorts
#define NUQ     16          // u-partial splits
// workspace layout (floats)
#define WS_U    8                          // 16*190
#define WS_PART 3048                       // part_h: 1024 * 3584 ushort = 1,835,008 floats
#define WS_PF   (3048 + 1835008)           // part_f: 1024 * 8 f32 (sumexp)
#define WS_AB   (WS_PF + 8192)             // ushort A_bf16[192*512] = 49152 floats
#define WS_WLB  (WS_AB + 49152)            // ushort Wlb[2048*512]

typedef __attribute__((ext_vector_type(8))) short  short8v;
typedef __attribute__((ext_vector_type(8))) unsigned short ushort8v;
typedef __attribute__((ext_vector_type(4))) float  f32x4;
typedef __attribute__((ext_vector_type(2))) unsigned int uint2v;

__device__ __forceinline__ float fast_tanh(float x) {
    float e = exp2f(x * 2.885390082f);
    return 1.0f - 2.0f * __builtin_amdgcn_rcpf(e + 1.0f);
}
__device__ __forceinline__ float fast_exp(float x) {
    return exp2f(x * 1.442695041f);
}
__device__ __forceinline__ unsigned short f2bf(float f) {   // RNE
    unsigned u = __float_as_uint(f);
    return (unsigned short)((u + 0x7FFFu + ((u >> 16) & 1u)) >> 16);
}
__device__ __forceinline__ float bf2f(unsigned short h) {
    return __uint_as_float((unsigned)h << 16);
}

// 64-lane sum, all lanes get result. PURE VALU: 4 DPP + permlane16/32_swap.
__device__ __forceinline__ float wave_sum(float v) {
    int x;
    x = __builtin_amdgcn_update_dpp(0, __float_as_int(v), 0xB1, 0xF, 0xF, true);
    v += __int_as_float(x);
    x = __builtin_amdgcn_update_dpp(0, __float_as_int(v), 0x4E, 0xF, 0xF, true);
    v += __int_as_float(x);
    x = __builtin_amdgcn_update_dpp(0, __float_as_int(v), 0x124, 0xF, 0xF, true);
    v += __int_as_float(x);
    x = __builtin_amdgcn_update_dpp(0, __float_as_int(v), 0x128, 0xF, 0xF, true);
    v += __int_as_float(x);
    uint2v p = __builtin_amdgcn_permlane16_swap(__float_as_uint(v), __float_as_uint(v), false, false);
    v = __uint_as_float(p[0]) + __uint_as_float(p[1]);
    p = __builtin_amdgcn_permlane32_swap(__float_as_uint(v), __float_as_uint(v), false, false);
    v = __uint_as_float(p[0]) + __uint_as_float(p[1]);
    return v;
}

// async global->LDS, 16B/lane; LDS dest = l + lane*16 (HW adds lane offset)
__device__ __forceinline__ void gload_lds16(const float* g, float* l) {
    __builtin_amdgcn_global_load_lds(
        (const __attribute__((address_space(1))) void*)g,
        (__attribute__((address_space(3))) void*)l, 16, 0, 0);
}

// ---------------- K0: u[q][k] = sum_{d in q*32..} Wr[d][k]*Wa[d] ----------------
__global__ __launch_bounds__(256) void k0_upart(
    const float* __restrict__ Wr, const float* __restrict__ Wa,
    float* __restrict__ ws_u) {
    const int q = blockIdx.x;           // 16 blocks, 32 d each
    const int k = threadIdx.x;
    if (k >= NROLES) return;
    float s = 0.f;
    const int d0 = q * 32;
    #pragma unroll 8
    for (int d = 0; d < 32; ++d)
        s += Wr[(size_t)(d0 + d) * NROLES + k] * Wa[d0 + d];
    ws_u[q * NROLES + k] = s;
}

// ---------------- K1: {fused main pass (1024 blk)} ∪ {Wl cast (512)} ∪ {verb (64)} ----------------
// cast/verb blocks backfill CU slots as main-pass blocks retire (overlap, not serial).
__global__ __launch_bounds__(256, 4) void k1_fused(
    const float* __restrict__ vs, const float* __restrict__ Wa,
    const float* __restrict__ roles, const float* __restrict__ br,
    const float* __restrict__ ba, const float* __restrict__ ws_u,
    unsigned short* __restrict__ part_h, float* __restrict__ part_f,
    const float* __restrict__ Wl, unsigned short* __restrict__ Wlb,
    const float* __restrict__ Wv, const float* __restrict__ bv,
    float* __restrict__ out_verb) {
    const int bid = blockIdx.x;
    const int tid = threadIdx.x;

    __shared__ __align__(16) float smem[4 * 2 * 1024];   // 32 KB rings; reused for merge / verb a_s
    __shared__ float lse_[4][R_];

    if (bid >= B_ * NSPLIT) {
        if (bid < B_ * NSPLIT + 512) {
            // ---- Wl cast: 2048 rows (pad >=2001 with 0), 512 cols ----
            const int ci = bid - B_ * NSPLIT;
            const int idx = ci * 2048 + tid * 8;
            const int row = idx >> 9;
            const int col = idx & 511;
            ushort8v o;
            if (row < VOCAB) {
                float4 a = *reinterpret_cast<const float4*>(Wl + (size_t)row * D_ + col);
                float4 b = *reinterpret_cast<const float4*>(Wl + (size_t)row * D_ + col + 4);
                o[0] = f2bf(a.x); o[1] = f2bf(a.y); o[2] = f2bf(a.z); o[3] = f2bf(a.w);
                o[4] = f2bf(b.x); o[5] = f2bf(b.y); o[6] = f2bf(b.z); o[7] = f2bf(b.w);
            } else {
                o = (ushort8v)0;
            }
            *reinterpret_cast<ushort8v*>(Wlb + idx) = o;
        } else {
            // ---- verb head ----
            const int q = bid - (B_ * NSPLIT + 512);   // 0..63
            const int b = q >> 1;
            const int g = q & 1;
            float* a_s = smem;
            float2 x = reinterpret_cast<const float2*>(vs + (size_t)b * (NP1 * D_))[tid];
            reinterpret_cast<float2*>(a_s)[tid] = make_float2(fmaxf(x.x, 0.f), fmaxf(x.y, 0.f));
            __syncthreads();
            const int v = g * 252 + tid;
            if (tid < 252 && v < NVERBS) {
                const float* wrow = Wv + (size_t)v * D_;
                float s = 0.f;
                #pragma unroll 4
                for (int k = 0; k < D_; k += 4) {
                    float4 w4 = *reinterpret_cast<const float4*>(wrow + k);
                    s += a_s[k] * w4.x + a_s[k + 1] * w4.y + a_s[k + 2] * w4.z + a_s[k + 3] * w4.w;
                }
                out_verb[b * NVERBS + v] = s + bv[v];
            }
        }
        return;
    }

    const int b     = bid / NSPLIT;
    const int split = bid % NSPLIT;
    const int lane  = tid & 63;
    const int w     = tid >> 6;
    float* ring = smem + w * 2048;

    const float4 wvA = *reinterpret_cast<const float4*>(Wa + D_ + lane * 4);
    const float4 wvB = *reinterpret_cast<const float4*>(Wa + D_ + 256 + lane * 4);

    const float* base = vs + (size_t)b * (NP1 * D_) + D_;
    const int n0 = split * CHUNK;
    const int nrows = min(n0 + CHUNK, NREG) - n0;    // 64 or 16
    const int cnt = (nrows - w + 3) >> 2;            // rows this wave (16 or 4)
    const int npairs = cnt >> 1;                     // 8 or 2

    // ---- stage first: get memory moving before the sr compute ----
    #pragma unroll
    for (int k = 0; k < 2; ++k) {
        const float* g0 = base + (size_t)(n0 + w + 8 * k) * D_ + lane * 4;
        float* s0 = ring + k * 1024;
        gload_lds16(g0, s0);
        gload_lds16(g0 + 256, s0 + 256);
        const float* g1 = g0 + 4 * D_;
        gload_lds16(g1, s0 + 512);
        gload_lds16(g1 + 256, s0 + 768);
    }
    asm volatile("" ::: "memory");

    // ---- inline s_role (L2-resident reads; overlaps ring latency) ----
    float sr[R_];
    {
        float pr[R_] = {0.f, 0.f, 0.f, 0.f, 0.f, 0.f};
        #pragma unroll
        for (int i = 0; i < 3; ++i) {
            const int k = lane + i * 64;
            if (k < NROLES) {
                float u = 0.f;
                #pragma unroll
                for (int q = 0; q < NUQ; ++q) u += ws_u[q * NROLES + k];
                #pragma unroll
                for (int r = 0; r < R_; ++r) pr[r] += roles[r * NROLES + k] * u;
            }
        }
        float c0 = 0.f;
        #pragma unroll
        for (int i = 0; i < 8; ++i) c0 += Wa[lane + i * 64] * br[lane + i * 64];
        c0 = wave_sum(c0) + ba[0];
        #pragma unroll
        for (int r = 0; r < R_; ++r) sr[r] = wave_sum(pr[r]) + c0;
    }

    float acc[R_][8];
    float rsum[8];
    float sume[R_];
    #pragma unroll
    for (int r = 0; r < R_; ++r) {
        sume[r] = 0.f;
        #pragma unroll
        for (int j = 0; j < 8; ++j) acc[r][j] = 0.f;
    }
    #pragma unroll
    for (int j = 0; j < 8; ++j) rsum[j] = 0.f;

    asm volatile("" ::: "memory");

    int st = 2;
    for (int p = 0; p < npairs; ++p) {
        const int rem = npairs - p;       // outstanding pairs = min(2, rem)
        if (rem > 1) asm volatile("s_waitcnt vmcnt(4)" ::: "memory");
        else         asm volatile("s_waitcnt vmcnt(0)" ::: "memory");

        const float* l0 = ring + (p & 1) * 1024;
        float4 x0A = *reinterpret_cast<const float4*>(l0 + lane * 4);
        float4 x0B = *reinterpret_cast<const float4*>(l0 + 256 + lane * 4);
        float4 x1A = *reinterpret_cast<const float4*>(l0 + 512 + lane * 4);
        float4 x1B = *reinterpret_cast<const float4*>(l0 + 768 + lane * 4);
        // consume (forces lgkm wait) BEFORE overwriting the slot
        float d0 = x0A.x*wvA.x + x0A.y*wvA.y + x0A.z*wvA.z + x0A.w*wvA.w
                 + x0B.x*wvB.x + x0B.y*wvB.y + x0B.z*wvB.z + x0B.w*wvB.w;
        float d1 = x1A.x*wvA.x + x1A.y*wvA.y + x1A.z*wvA.z + x1A.w*wvA.w
                 + x1B.x*wvB.x + x1B.y*wvB.y + x1B.z*wvB.z + x1B.w*wvB.w;
        if (st < npairs) {                 // refill the slot just consumed
            const float* g0 = base + (size_t)(n0 + w + 8 * st) * D_ + lane * 4;
            float* s0 = ring + (st & 1) * 1024;
            gload_lds16(g0, s0);
            gload_lds16(g0 + 256, s0 + 256);
            const float* g1 = g0 + 4 * D_;
            gload_lds16(g1, s0 + 512);
            gload_lds16(g1 + 256, s0 + 768);
            ++st;
        }
        d0 = wave_sum(d0);
        d1 = wave_sum(d1);
        float xs0[8] = {x0A.x,x0A.y,x0A.z,x0A.w,x0B.x,x0B.y,x0B.z,x0B.w};
        float xs1[8] = {x1A.x,x1A.y,x1A.z,x1A.w,x1B.x,x1B.y,x1B.z,x1B.w};
        #pragma unroll
        for (int r = 0; r < R_; ++r) {
            float t0 = fast_tanh(sr[r] + d0);
            float t1 = fast_tanh(sr[r] + d1);
            sume[r] += fast_exp(t0) + fast_exp(t1);
            #pragma unroll
            for (int j = 0; j < 8; ++j) acc[r][j] += t0 * xs0[j] + t1 * xs1[j];
        }
        #pragma unroll
        for (int j = 0; j < 8; ++j) rsum[j] += xs0[j] + xs1[j];
    }

    // merge the 4 waves into smem[0..3583] (reused -> barrier first)
    __syncthreads();
    float* ls = smem;
    for (int ww = 0; ww < 4; ++ww) {
        if (w == ww) {
            #pragma unroll
            for (int j = 0; j < 8; ++j) {
                const int dd = (j < 4) ? (lane * 4 + j) : (256 + lane * 4 + (j - 4));
                if (ww == 0) {
                    #pragma unroll
                    for (int r = 0; r < R_; ++r) ls[r * D_ + dd] = acc[r][j];
                    ls[6 * D_ + dd] = rsum[j];
                } else {
                    #pragma unroll
                    for (int r = 0; r < R_; ++r) ls[r * D_ + dd] += acc[r][j];
                    ls[6 * D_ + dd] += rsum[j];
                }
            }
            if (lane == 0) {
                #pragma unroll
                for (int r = 0; r < R_; ++r) lse_[ww][r] = sume[r];
            }
        }
        __syncthreads();
    }
    // bf16 partial write: 3584 values = 448 x ushort8
    unsigned short* dsth = part_h + (size_t)(b * NSPLIT + split) * PH_STRIDE;
    for (int i = tid; i < 448; i += 256) {
        float4 a = reinterpret_cast<const float4*>(ls)[i * 2];
        float4 c = reinterpret_cast<const float4*>(ls)[i * 2 + 1];
        ushort8v o;
        o[0] = f2bf(a.x); o[1] = f2bf(a.y); o[2] = f2bf(a.z); o[3] = f2bf(a.w);
        o[4] = f2bf(c.x); o[5] = f2bf(c.y); o[6] = f2bf(c.z); o[7] = f2bf(c.w);
        reinterpret_cast<ushort8v*>(dsth)[i] = o;
    }
    if (tid < R_)
        part_f[(size_t)(b * NSPLIT + split) * 8 + tid] =
            lse_[0][tid] + lse_[1][tid] + lse_[2][tid] + lse_[3][tid];
}

// ---------------- K2: reduce bf16 partials -> relu(label_embed) as bf16 ----------------
__global__ __launch_bounds__(256) void k2_reduce(
    const unsigned short* __restrict__ part_h, const float* __restrict__ part_f,
    unsigned short* __restrict__ AB) {
    const int bid = blockIdx.x;
    const int t = threadIdx.x;
    const int b = bid >> 3;
    const int chunk = bid & 7;
    const int dl = t & 63;
    const int qg = t >> 6;
    const int d = chunk * 64 + dl;
    const unsigned short* pb = part_h + (size_t)b * NSPLIT * PH_STRIDE;

    float s[7] = {0.f, 0.f, 0.f, 0.f, 0.f, 0.f, 0.f};
    for (int q = qg * 8; q < qg * 8 + 8; ++q) {
        const unsigned short* p = pb + (size_t)q * PH_STRIDE;
        #pragma unroll
        for (int r = 0; r < R_; ++r) s[r] += bf2f(p[r * D_ + d]);
        s[6] += bf2f(p[6 * D_ + d]);
    }
    __shared__ float red[4][7][64];
    #pragma unroll
    for (int i = 0; i < 7; ++i) red[qg][i][dl] = s[i];
    __shared__ float lse_s[R_];
    if (t < R_) {
        float se = 0.f;
        const float* pf = part_f + (size_t)b * NSPLIT * 8;
        for (int q = 0; q < NSPLIT; ++q) se += pf[q * 8 + t];
        lse_s[t] = logf(se);
    }
    __syncthreads();
    if (t < 64) {
        float rs = red[0][6][dl] + red[1][6][dl] + red[2][6][dl] + red[3][6][dl];
        #pragma unroll
        for (int r = 0; r < R_; ++r) {
            float sw = red[0][r][dl] + red[1][r][dl] + red[2][r][dl] + red[3][r][dl];
            AB[(size_t)(b * R_ + r) * D_ + d] = f2bf(fmaxf(sw - lse_s[r] * rs, 0.f));
        }
    }
}

// ---------------- K3: bf16 MFMA gemm, out = relu(A) @ Wl^T + bl ----------------
// one wave-tile (16m x 64v) per 64-thread block; 384 blocks -> all CUs busy.
__global__ __launch_bounds__(64) void k3_mfma(
    const unsigned short* __restrict__ AB, const unsigned short* __restrict__ Wlb,
    const float* __restrict__ bl, float* __restrict__ out_role) {
    const int lane = threadIdx.x;
    const int wt   = blockIdx.x;             // 0..383
    const int mt   = wt >> 5;                // 0..11
    const int vt   = wt & 31;                // 0..31
    const int m0   = mt * 16;
    const int v0   = vt * 64;
    const int rc   = lane & 15;              // A-row (m) and B-col (v) sub-index
    const int kg   = lane >> 4;              // k-group

    const unsigned short* arow = AB + (size_t)(m0 + rc) * D_ + kg * 8;
    f32x4 acc0 = {0.f, 0.f, 0.f, 0.f}, acc1 = {0.f, 0.f, 0.f, 0.f};
    f32x4 acc2 = {0.f, 0.f, 0.f, 0.f}, acc3 = {0.f, 0.f, 0.f, 0.f};

    #pragma unroll 4
    for (int ks = 0; ks < 16; ++ks) {
        const int kb = ks * 32;
        short8v af = *reinterpret_cast<const short8v*>(arow + kb);
        const unsigned short* wb = Wlb + (size_t)(v0 + rc) * D_ + kg * 8 + kb;
        short8v b0 = *reinterpret_cast<const short8v*>(wb);
        short8v b1 = *reinterpret_cast<const short8v*>(wb + 16 * D_);
        short8v b2 = *reinterpret_cast<const short8v*>(wb + 32 * D_);
        short8v b3 = *reinterpret_cast<const short8v*>(wb + 48 * D_);
        acc0 = __builtin_amdgcn_mfma_f32_16x16x32_bf16(af, b0, acc0, 0, 0, 0);
        acc1 = __builtin_amdgcn_mfma_f32_16x16x32_bf16(af, b1, acc1, 0, 0, 0);
        acc2 = __builtin_amdgcn_mfma_f32_16x16x32_bf16(af, b2, acc2, 0, 0, 0);
        acc3 = __builtin_amdgcn_mfma_f32_16x16x32_bf16(af, b3, acc3, 0, 0, 0);
    }
    f32x4 accs[4] = {acc0, acc1, acc2, acc3};
    #pragma unroll
    for (int f = 0; f < 4; ++f) {
        const int v = v0 + f * 16 + rc;
        if (v < VOCAB) {
            const float bb = bl[v];
            #pragma unroll
            for (int j = 0; j < 4; ++j) {
                const int m = m0 + kg * 4 + j;
                out_role[(size_t)m * VOCAB + v] = accs[f][j] + bb;
            }
        }
    }
}

extern "C" void kernel_launch(void* const* d_in, const int* in_sizes, int n_in,
                              void* d_out, int out_size, void* d_ws, size_t ws_size,
                              hipStream_t stream) {
    const float* vs    = (const float*)d_in[0];
    const float* roles = (const float*)d_in[1];
    const float* Wr    = (const float*)d_in[2];
    const float* br    = (const float*)d_in[3];
    const float* Wa    = (const float*)d_in[4];
    const float* ba    = (const float*)d_in[5];
    const float* Wv    = (const float*)d_in[6];
    const float* bv    = (const float*)d_in[7];
    const float* Wl    = (const float*)d_in[8];
    const float* bl    = (const float*)d_in[9];

    float* out_verb = (float*)d_out;
    float* out_role = (float*)d_out + B_ * NVERBS;
    float* ws       = (float*)d_ws;
    unsigned short* part_h = (unsigned short*)(ws + WS_PART);
    float*          part_f = ws + WS_PF;
    unsigned short* AB     = (unsigned short*)(ws + WS_AB);
    unsigned short* Wlb    = (unsigned short*)(ws + WS_WLB);

    k0_upart<<<dim3(NUQ), dim3(256), 0, stream>>>(Wr, Wa, ws + WS_U);
    k1_fused<<<dim3(B_ * NSPLIT + 512 + 64), dim3(256), 0, stream>>>(
        vs, Wa, roles, br, ba, ws + WS_U, part_h, part_f,
        Wl, Wlb, Wv, bv, out_verb);
    k2_reduce<<<dim3(256), dim3(256), 0, stream>>>(part_h, part_f, AB);
    k3_mfma<<<dim3(384), dim3(64), 0, stream>>>(AB, Wlb, bl, out_role);
}

// Round 20
// 59.494 us; speedup vs baseline: 1.1586x; 1.0023x over previous
//
#include <hip/hip_runtime.h>
#include <math.h>

#define B_      32
#define NP1     2001
#define D_      512
#define R_      6
#define NROLES  190
#define NVERBS  504
#define VOCAB   2001
#define NREG    2000

#define NSPLIT  32
#define CHUNK   64
#define PH_STRIDE 3584      // bf16 partial stride (6*512 SW + 512 rsum) in ushorts
#define NUQ     16          // u-partial splits
// workspace layout (floats)
#define WS_U    8                          // 16*190
#define WS_PART 3048                       // part_h: 1024 * 3584 ushort = 1,835,008 floats
#define WS_PF   (3048 + 1835008)           // part_f: 1024 * 8 f32 (sumexp)
#define WS_AB   (WS_PF + 8192)             // ushort A_bf16[192*512] = 49152 floats
#define WS_WLB  (WS_AB + 49152)            // ushort Wlb[2048*512]

typedef __attribute__((ext_vector_type(8))) short  short8v;
typedef __attribute__((ext_vector_type(8))) unsigned short ushort8v;
typedef __attribute__((ext_vector_type(4))) float  f32x4;
typedef __attribute__((ext_vector_type(2))) unsigned int uint2v;

__device__ __forceinline__ float fast_tanh(float x) {
    float e = exp2f(x * 2.885390082f);
    return 1.0f - 2.0f * __builtin_amdgcn_rcpf(e + 1.0f);
}
__device__ __forceinline__ float fast_exp(float x) {
    return exp2f(x * 1.442695041f);
}
__device__ __forceinline__ unsigned short f2bf(float f) {   // RNE
    unsigned u = __float_as_uint(f);
    return (unsigned short)((u + 0x7FFFu + ((u >> 16) & 1u)) >> 16);
}
__device__ __forceinline__ float bf2f(unsigned short h) {
    return __uint_as_float((unsigned)h << 16);
}

// 64-lane sum, all lanes get result. PURE VALU: 4 DPP + permlane16/32_swap.
__device__ __forceinline__ float wave_sum(float v) {
    int x;
    x = __builtin_amdgcn_update_dpp(0, __float_as_int(v), 0xB1, 0xF, 0xF, true);
    v += __int_as_float(x);
    x = __builtin_amdgcn_update_dpp(0, __float_as_int(v), 0x4E, 0xF, 0xF, true);
    v += __int_as_float(x);
    x = __builtin_amdgcn_update_dpp(0, __float_as_int(v), 0x124, 0xF, 0xF, true);
    v += __int_as_float(x);
    x = __builtin_amdgcn_update_dpp(0, __float_as_int(v), 0x128, 0xF, 0xF, true);
    v += __int_as_float(x);
    uint2v p = __builtin_amdgcn_permlane16_swap(__float_as_uint(v), __float_as_uint(v), false, false);
    v = __uint_as_float(p[0]) + __uint_as_float(p[1]);
    p = __builtin_amdgcn_permlane32_swap(__float_as_uint(v), __float_as_uint(v), false, false);
    v = __uint_as_float(p[0]) + __uint_as_float(p[1]);
    return v;
}

// async global->LDS, 16B/lane; LDS dest = l + lane*16 (HW adds lane offset)
__device__ __forceinline__ void gload_lds16(const float* g, float* l) {
    __builtin_amdgcn_global_load_lds(
        (const __attribute__((address_space(1))) void*)g,
        (__attribute__((address_space(3))) void*)l, 16, 0, 0);
}

// ---------------- K0: u[q][k] = sum_{d in q*32..} Wr[d][k]*Wa[d] ----------------
__global__ __launch_bounds__(256) void k0_upart(
    const float* __restrict__ Wr, const float* __restrict__ Wa,
    float* __restrict__ ws_u) {
    const int q = blockIdx.x;           // 16 blocks, 32 d each
    const int k = threadIdx.x;
    if (k >= NROLES) return;
    float s = 0.f;
    const int d0 = q * 32;
    #pragma unroll 8
    for (int d = 0; d < 32; ++d)
        s += Wr[(size_t)(d0 + d) * NROLES + k] * Wa[d0 + d];
    ws_u[q * NROLES + k] = s;
}

// ---------------- K1: {fused main pass (1024 blk)} ∪ {Wl cast (512)} ∪ {verb (64)} ----------------
// cast/verb blocks backfill CU slots as main-pass blocks retire (overlap, not serial).
__global__ __launch_bounds__(256, 4) void k1_fused(
    const float* __restrict__ vs, const float* __restrict__ Wa,
    const float* __restrict__ roles, const float* __restrict__ br,
    const float* __restrict__ ba, const float* __restrict__ ws_u,
    unsigned short* __restrict__ part_h, float* __restrict__ part_f,
    const float* __restrict__ Wl, unsigned short* __restrict__ Wlb,
    const float* __restrict__ Wv, const float* __restrict__ bv,
    float* __restrict__ out_verb) {
    const int bid = blockIdx.x;
    const int tid = threadIdx.x;

    __shared__ __align__(16) float smem[4 * 2 * 1024];   // 32 KB rings; reused for merge / verb a_s
    __shared__ float lse_[4][R_];

    if (bid >= B_ * NSPLIT) {
        if (bid < B_ * NSPLIT + 512) {
            // ---- Wl cast: 2048 rows (pad >=2001 with 0), 512 cols ----
            const int ci = bid - B_ * NSPLIT;
            const int idx = ci * 2048 + tid * 8;
            const int row = idx >> 9;
            const int col = idx & 511;
            ushort8v o;
            if (row < VOCAB) {
                float4 a = *reinterpret_cast<const float4*>(Wl + (size_t)row * D_ + col);
                float4 b = *reinterpret_cast<const float4*>(Wl + (size_t)row * D_ + col + 4);
                o[0] = f2bf(a.x); o[1] = f2bf(a.y); o[2] = f2bf(a.z); o[3] = f2bf(a.w);
                o[4] = f2bf(b.x); o[5] = f2bf(b.y); o[6] = f2bf(b.z); o[7] = f2bf(b.w);
            } else {
                o = (ushort8v)0;
            }
            *reinterpret_cast<ushort8v*>(Wlb + idx) = o;
        } else {
            // ---- verb head ----
            const int q = bid - (B_ * NSPLIT + 512);   // 0..63
            const int b = q >> 1;
            const int g = q & 1;
            float* a_s = smem;
            float2 x = reinterpret_cast<const float2*>(vs + (size_t)b * (NP1 * D_))[tid];
            reinterpret_cast<float2*>(a_s)[tid] = make_float2(fmaxf(x.x, 0.f), fmaxf(x.y, 0.f));
            __syncthreads();
            const int v = g * 252 + tid;
            if (tid < 252 && v < NVERBS) {
                const float* wrow = Wv + (size_t)v * D_;
                float s = 0.f;
                #pragma unroll 4
                for (int k = 0; k < D_; k += 4) {
                    float4 w4 = *reinterpret_cast<const float4*>(wrow + k);
                    s += a_s[k] * w4.x + a_s[k + 1] * w4.y + a_s[k + 2] * w4.z + a_s[k + 3] * w4.w;
                }
                out_verb[b * NVERBS + v] = s + bv[v];
            }
        }
        return;
    }

    const int b     = bid / NSPLIT;
    const int split = bid % NSPLIT;
    const int lane  = tid & 63;
    const int w     = tid >> 6;
    float* ring = smem + w * 2048;

    const float4 wvA = *reinterpret_cast<const float4*>(Wa + D_ + lane * 4);
    const float4 wvB = *reinterpret_cast<const float4*>(Wa + D_ + 256 + lane * 4);

    const float* base = vs + (size_t)b * (NP1 * D_) + D_;
    const int n0 = split * CHUNK;
    const int nrows = min(n0 + CHUNK, NREG) - n0;    // 64 or 16
    const int cnt = (nrows - w + 3) >> 2;            // rows this wave (16 or 4)
    const int npairs = cnt >> 1;                     // 8 or 2

    // ---- stage first: get memory moving before the sr compute ----
    #pragma unroll
    for (int k = 0; k < 2; ++k) {
        const float* g0 = base + (size_t)(n0 + w + 8 * k) * D_ + lane * 4;
        float* s0 = ring + k * 1024;
        gload_lds16(g0, s0);
        gload_lds16(g0 + 256, s0 + 256);
        const float* g1 = g0 + 4 * D_;
        gload_lds16(g1, s0 + 512);
        gload_lds16(g1 + 256, s0 + 768);
    }
    asm volatile("" ::: "memory");

    // ---- inline s_role (L2-resident reads; overlaps ring latency) ----
    float sr[R_];
    {
        float pr[R_] = {0.f, 0.f, 0.f, 0.f, 0.f, 0.f};
        #pragma unroll
        for (int i = 0; i < 3; ++i) {
            const int k = lane + i * 64;
            if (k < NROLES) {
                float u = 0.f;
                #pragma unroll
                for (int q = 0; q < NUQ; ++q) u += ws_u[q * NROLES + k];
                #pragma unroll
                for (int r = 0; r < R_; ++r) pr[r] += roles[r * NROLES + k] * u;
            }
        }
        float c0 = 0.f;
        #pragma unroll
        for (int i = 0; i < 8; ++i) c0 += Wa[lane + i * 64] * br[lane + i * 64];
        c0 = wave_sum(c0) + ba[0];
        #pragma unroll
        for (int r = 0; r < R_; ++r) sr[r] = wave_sum(pr[r]) + c0;
    }

    float acc[R_][8];
    float rsum[8];
    float sume[R_];
    #pragma unroll
    for (int r = 0; r < R_; ++r) {
        sume[r] = 0.f;
        #pragma unroll
        for (int j = 0; j < 8; ++j) acc[r][j] = 0.f;
    }
    #pragma unroll
    for (int j = 0; j < 8; ++j) rsum[j] = 0.f;

    asm volatile("" ::: "memory");

    int st = 2;
    for (int p = 0; p < npairs; ++p) {
        const int rem = npairs - p;       // outstanding pairs = min(2, rem)
        if (rem > 1) asm volatile("s_waitcnt vmcnt(4)" ::: "memory");
        else         asm volatile("s_waitcnt vmcnt(0)" ::: "memory");

        const float* l0 = ring + (p & 1) * 1024;
        float4 x0A = *reinterpret_cast<const float4*>(l0 + lane * 4);
        float4 x0B = *reinterpret_cast<const float4*>(l0 + 256 + lane * 4);
        float4 x1A = *reinterpret_cast<const float4*>(l0 + 512 + lane * 4);
        float4 x1B = *reinterpret_cast<const float4*>(l0 + 768 + lane * 4);
        // consume (forces lgkm wait) BEFORE overwriting the slot
        float d0 = x0A.x*wvA.x + x0A.y*wvA.y + x0A.z*wvA.z + x0A.w*wvA.w
                 + x0B.x*wvB.x + x0B.y*wvB.y + x0B.z*wvB.z + x0B.w*wvB.w;
        float d1 = x1A.x*wvA.x + x1A.y*wvA.y + x1A.z*wvA.z + x1A.w*wvA.w
                 + x1B.x*wvB.x + x1B.y*wvB.y + x1B.z*wvB.z + x1B.w*wvB.w;
        if (st < npairs) {                 // refill the slot just consumed
            const float* g0 = base + (size_t)(n0 + w + 8 * st) * D_ + lane * 4;
            float* s0 = ring + (st & 1) * 1024;
            gload_lds16(g0, s0);
            gload_lds16(g0 + 256, s0 + 256);
            const float* g1 = g0 + 4 * D_;
            gload_lds16(g1, s0 + 512);
            gload_lds16(g1 + 256, s0 + 768);
            ++st;
        }
        d0 = wave_sum(d0);
        d1 = wave_sum(d1);
        float xs0[8] = {x0A.x,x0A.y,x0A.z,x0A.w,x0B.x,x0B.y,x0B.z,x0B.w};
        float xs1[8] = {x1A.x,x1A.y,x1A.z,x1A.w,x1B.x,x1B.y,x1B.z,x1B.w};
        #pragma unroll
        for (int r = 0; r < R_; ++r) {
            float t0 = fast_tanh(sr[r] + d0);
            float t1 = fast_tanh(sr[r] + d1);
            sume[r] += fast_exp(t0) + fast_exp(t1);
            #pragma unroll
            for (int j = 0; j < 8; ++j) acc[r][j] += t0 * xs0[j] + t1 * xs1[j];
        }
        #pragma unroll
        for (int j = 0; j < 8; ++j) rsum[j] += xs0[j] + xs1[j];
    }

    // merge the 4 waves into smem[0..3583] (reused -> barrier first)
    __syncthreads();
    float* ls = smem;
    for (int ww = 0; ww < 4; ++ww) {
        if (w == ww) {
            #pragma unroll
            for (int j = 0; j < 8; ++j) {
                const int dd = (j < 4) ? (lane * 4 + j) : (256 + lane * 4 + (j - 4));
                if (ww == 0) {
                    #pragma unroll
                    for (int r = 0; r < R_; ++r) ls[r * D_ + dd] = acc[r][j];
                    ls[6 * D_ + dd] = rsum[j];
                } else {
                    #pragma unroll
                    for (int r = 0; r < R_; ++r) ls[r * D_ + dd] += acc[r][j];
                    ls[6 * D_ + dd] += rsum[j];
                }
            }
            if (lane == 0) {
                #pragma unroll
                for (int r = 0; r < R_; ++r) lse_[ww][r] = sume[r];
            }
        }
        __syncthreads();
    }
    // bf16 partial write: 3584 values = 448 x ushort8
    unsigned short* dsth = part_h + (size_t)(b * NSPLIT + split) * PH_STRIDE;
    for (int i = tid; i < 448; i += 256) {
        float4 a = reinterpret_cast<const float4*>(ls)[i * 2];
        float4 c = reinterpret_cast<const float4*>(ls)[i * 2 + 1];
        ushort8v o;
        o[0] = f2bf(a.x); o[1] = f2bf(a.y); o[2] = f2bf(a.z); o[3] = f2bf(a.w);
        o[4] = f2bf(c.x); o[5] = f2bf(c.y); o[6] = f2bf(c.z); o[7] = f2bf(c.w);
        reinterpret_cast<ushort8v*>(dsth)[i] = o;
    }
    if (tid < R_)
        part_f[(size_t)(b * NSPLIT + split) * 8 + tid] =
            lse_[0][tid] + lse_[1][tid] + lse_[2][tid] + lse_[3][tid];
}

// ---------------- K2: reduce bf16 partials -> relu(label_embed) as bf16 ----------------
__global__ __launch_bounds__(256) void k2_reduce(
    const unsigned short* __restrict__ part_h, const float* __restrict__ part_f,
    unsigned short* __restrict__ AB) {
    const int bid = blockIdx.x;
    const int t = threadIdx.x;
    const int b = bid >> 3;
    const int chunk = bid & 7;
    const int dl = t & 63;
    const int qg = t >> 6;
    const int d = chunk * 64 + dl;
    const unsigned short* pb = part_h + (size_t)b * NSPLIT * PH_STRIDE;

    float s[7] = {0.f, 0.f, 0.f, 0.f, 0.f, 0.f, 0.f};
    for (int q = qg * 8; q < qg * 8 + 8; ++q) {
        const unsigned short* p = pb + (size_t)q * PH_STRIDE;
        #pragma unroll
        for (int r = 0; r < R_; ++r) s[r] += bf2f(p[r * D_ + d]);
        s[6] += bf2f(p[6 * D_ + d]);
    }
    __shared__ float red[4][7][64];
    #pragma unroll
    for (int i = 0; i < 7; ++i) red[qg][i][dl] = s[i];
    __shared__ float lse_s[R_];
    if (t < R_) {
        float se = 0.f;
        const float* pf = part_f + (size_t)b * NSPLIT * 8;
        for (int q = 0; q < NSPLIT; ++q) se += pf[q * 8 + t];
        lse_s[t] = logf(se);
    }
    __syncthreads();
    if (t < 64) {
        float rs = red[0][6][dl] + red[1][6][dl] + red[2][6][dl] + red[3][6][dl];
        #pragma unroll
        for (int r = 0; r < R_; ++r) {
            float sw = red[0][r][dl] + red[1][r][dl] + red[2][r][dl] + red[3][r][dl];
            AB[(size_t)(b * R_ + r) * D_ + d] = f2bf(fmaxf(sw - lse_s[r] * rs, 0.f));
        }
    }
}

// ---------------- K3: bf16 MFMA gemm, out = relu(A) @ Wl^T + bl ----------------
// one wave-tile (16m x 64v) per 64-thread block; 384 blocks -> all CUs busy.
__global__ __launch_bounds__(64) void k3_mfma(
    const unsigned short* __restrict__ AB, const unsigned short* __restrict__ Wlb,
    const float* __restrict__ bl, float* __restrict__ out_role) {
    const int lane = threadIdx.x;
    const int wt   = blockIdx.x;             // 0..383
    const int mt   = wt >> 5;                // 0..11
    const int vt   = wt & 31;                // 0..31
    const int m0   = mt * 16;
    const int v0   = vt * 64;
    const int rc   = lane & 15;              // A-row (m) and B-col (v) sub-index
    const int kg   = lane >> 4;              // k-group

    const unsigned short* arow = AB + (size_t)(m0 + rc) * D_ + kg * 8;
    f32x4 acc0 = {0.f, 0.f, 0.f, 0.f}, acc1 = {0.f, 0.f, 0.f, 0.f};
    f32x4 acc2 = {0.f, 0.f, 0.f, 0.f}, acc3 = {0.f, 0.f, 0.f, 0.f};

    #pragma unroll 4
    for (int ks = 0; ks < 16; ++ks) {
        const int kb = ks * 32;
        short8v af = *reinterpret_cast<const short8v*>(arow + kb);
        const unsigned short* wb = Wlb + (size_t)(v0 + rc) * D_ + kg * 8 + kb;
        short8v b0 = *reinterpret_cast<const short8v*>(wb);
        short8v b1 = *reinterpret_cast<const short8v*>(wb + 16 * D_);
        short8v b2 = *reinterpret_cast<const short8v*>(wb + 32 * D_);
        short8v b3 = *reinterpret_cast<const short8v*>(wb + 48 * D_);
        acc0 = __builtin_amdgcn_mfma_f32_16x16x32_bf16(af, b0, acc0, 0, 0, 0);
        acc1 = __builtin_amdgcn_mfma_f32_16x16x32_bf16(af, b1, acc1, 0, 0, 0);
        acc2 = __builtin_amdgcn_mfma_f32_16x16x32_bf16(af, b2, acc2, 0, 0, 0);
        acc3 = __builtin_amdgcn_mfma_f32_16x16x32_bf16(af, b3, acc3, 0, 0, 0);
    }
    f32x4 accs[4] = {acc0, acc1, acc2, acc3};
    #pragma unroll
    for (int f = 0; f < 4; ++f) {
        const int v = v0 + f * 16 + rc;
        if (v < VOCAB) {
            const float bb = bl[v];
            #pragma unroll
            for (int j = 0; j < 4; ++j) {
                const int m = m0 + kg * 4 + j;
                out_role[(size_t)m * VOCAB + v] = accs[f][j] + bb;
            }
        }
    }
}

extern "C" void kernel_launch(void* const* d_in, const int* in_sizes, int n_in,
                              void* d_out, int out_size, void* d_ws, size_t ws_size,
                              hipStream_t stream) {
    const float* vs    = (const float*)d_in[0];
    const float* roles = (const float*)d_in[1];
    const float* Wr    = (const float*)d_in[2];
    const float* br    = (const float*)d_in[3];
    const float* Wa    = (const float*)d_in[4];
    const float* ba    = (const float*)d_in[5];
    const float* Wv    = (const float*)d_in[6];
    const float* bv    = (const float*)d_in[7];
    const float* Wl    = (const float*)d_in[8];
    const float* bl    = (const float*)d_in[9];

    float* out_verb = (float*)d_out;
    float* out_role = (float*)d_out + B_ * NVERBS;
    float* ws       = (float*)d_ws;
    unsigned short* part_h = (unsigned short*)(ws + WS_PART);
    float*          part_f = ws + WS_PF;
    unsigned short* AB     = (unsigned short*)(ws + WS_AB);
    unsigned short* Wlb    = (unsigned short*)(ws + WS_WLB);

    k0_upart<<<dim3(NUQ), dim3(256), 0, stream>>>(Wr, Wa, ws + WS_U);
    k1_fused<<<dim3(B_ * NSPLIT + 512 + 64), dim3(256), 0, stream>>>(
        vs, Wa, roles, br, ba, ws + WS_U, part_h, part_f,
        Wl, Wlb, Wv, bv, out_verb);
    k2_reduce<<<dim3(256), dim3(256), 0, stream>>>(part_h, part_f, AB);
    k3_mfma<<<dim3(384), dim3(64), 0, stream>>>(AB, Wlb, bl, out_role);
}